// Round 2
// baseline (801.089 us; speedup 1.0000x reference)
//
#include <hip/hip_runtime.h>
#include <hip/hip_bf16.h>

#define N_NODES 50000
#define N_EDGES 800000
#define ET (N_EDGES + N_NODES)   // edges + self loops = 850000
#define IN_DIM 128
#define F1 256                   // H1*HID
#define H1 4
#define HID 64
#define H2 2
#define OUTC 8
#define F2 16                    // H2*OUTC

static __device__ __forceinline__ float lrelu(float x) { return x > 0.f ? x : 0.2f * x; }
static __device__ __forceinline__ float eluf(float x) { return x > 0.f ? x : __expf(x) - 1.f; }

// ---------------- CSR build ----------------
__global__ void zero_kernel(int* p, int n) {
    int i = blockIdx.x * blockDim.x + threadIdx.x;
    if (i < n) p[i] = 0;
}

// edge_index arrives as int32 (harness converts integer inputs to int32).
__global__ void hist_kernel(const int* __restrict__ ei, int* __restrict__ deg) {
    int e = blockIdx.x * blockDim.x + threadIdx.x;
    if (e >= ET) return;
    int dst = (e < N_EDGES) ? ei[N_EDGES + e] : (e - N_EDGES);
    atomicAdd(&deg[dst], 1);
}

#define SCAN_NT 1024
__global__ __launch_bounds__(SCAN_NT) void scan_kernel(int* __restrict__ deg /*in: counts, out: cursor*/,
                                                       int* __restrict__ off) {
    __shared__ int sums[SCAN_NT];
    const int ITEMS = (N_NODES + SCAN_NT - 1) / SCAN_NT;  // 49
    int t = threadIdx.x;
    int base = t * ITEMS;
    int s = 0;
    for (int i = 0; i < ITEMS; i++) {
        int idx = base + i;
        if (idx < N_NODES) s += deg[idx];
    }
    sums[t] = s;
    __syncthreads();
    for (int d = 1; d < SCAN_NT; d <<= 1) {
        int v = (t >= d) ? sums[t - d] : 0;
        __syncthreads();
        sums[t] += v;
        __syncthreads();
    }
    int run = (t == 0) ? 0 : sums[t - 1];
    for (int i = 0; i < ITEMS; i++) {
        int idx = base + i;
        if (idx < N_NODES) {
            int v = deg[idx];
            off[idx] = run;
            deg[idx] = run;  // becomes cursor for scatter
            run += v;
        }
    }
    if (t == SCAN_NT - 1) off[N_NODES] = run;
}

__global__ void scatter_kernel(const int* __restrict__ ei, int* __restrict__ cursor,
                               int* __restrict__ csr_src) {
    int e = blockIdx.x * blockDim.x + threadIdx.x;
    if (e >= ET) return;
    int src, dst;
    if (e < N_EDGES) {
        src = ei[e];
        dst = ei[N_EDGES + e];
    } else {
        src = dst = e - N_EDGES;
    }
    int pos = atomicAdd(&cursor[dst], 1);
    csr_src[pos] = src;
}

// ---------------- GEMM1: h_lin = x @ W_feat, plus alpha reductions ----------------
// block 256 threads = 32 nodes x 256 cols; x tile staged in LDS.
__global__ __launch_bounds__(256) void gemm1_kernel(const float* __restrict__ x,
                                                    const float* __restrict__ Wf,
                                                    const float* __restrict__ a_src,
                                                    const float* __restrict__ a_dst,
                                                    float* __restrict__ h_lin,
                                                    float* __restrict__ al_s,
                                                    float* __restrict__ al_d) {
    __shared__ float xt[32 * 128];
    int tid = threadIdx.x;
    int node0 = blockIdx.x * 32;
    const float4* xg = reinterpret_cast<const float4*>(x) + (size_t)node0 * 32;
    float4* xt4 = reinterpret_cast<float4*>(xt);
    int maxf4 = (N_NODES - node0) * 32;
#pragma unroll
    for (int i = 0; i < 4; i++) {
        int f4 = tid + i * 256;
        float4 v = make_float4(0.f, 0.f, 0.f, 0.f);
        if (f4 < maxf4) v = xg[f4];
        xt4[f4] = v;
    }
    __syncthreads();

    float acc[32];
#pragma unroll
    for (int r = 0; r < 32; r++) acc[r] = 0.f;
    int j = tid;
    for (int kc = 0; kc < 128; kc += 8) {
        float w[8];
#pragma unroll
        for (int kk = 0; kk < 8; kk++) w[kk] = Wf[(kc + kk) * 256 + j];
#pragma unroll
        for (int r = 0; r < 32; r++) {
            float4 a0 = xt4[r * 32 + (kc >> 2)];
            float4 a1 = xt4[r * 32 + (kc >> 2) + 1];
            acc[r] += a0.x * w[0] + a0.y * w[1] + a0.z * w[2] + a0.w * w[3] +
                      a1.x * w[4] + a1.y * w[5] + a1.z * w[6] + a1.w * w[7];
        }
    }
    // write h_lin (coalesced)
    for (int r = 0; r < 32; r++) {
        int node = node0 + r;
        if (node < N_NODES) h_lin[(size_t)node * 256 + j] = acc[r];
    }
    // alpha reductions: wave w == head w (4 waves, 64 lanes = 64 channels of that head)
    int head = tid >> 6;
    int lane = tid & 63;
    float asv = a_src[head * 64 + lane];
    float adv = a_dst[head * 64 + lane];
    for (int r = 0; r < 32; r++) {
        float ps = acc[r] * asv;
        float pd = acc[r] * adv;
#pragma unroll
        for (int d = 1; d < 64; d <<= 1) {
            ps += __shfl_xor(ps, d);
            pd += __shfl_xor(pd, d);
        }
        int node = node0 + r;
        if (lane == 0 && node < N_NODES) {
            al_s[node * 4 + head] = ps;
            al_d[node * 4 + head] = pd;
        }
    }
}

// ---------------- conv1 aggregation: one wave per dst node ----------------
__global__ __launch_bounds__(256) void conv1_aggregate(const int* __restrict__ deg_off,
                                                       const int* __restrict__ csr_src,
                                                       const float* __restrict__ h_lin,
                                                       const float* __restrict__ al_s,
                                                       const float* __restrict__ al_d,
                                                       const float* __restrict__ b_feat,
                                                       float* __restrict__ h1) {
    int wave = threadIdx.x >> 6;
    int lane = threadIdx.x & 63;
    int node = blockIdx.x * 4 + wave;
    if (node >= N_NODES) return;
    int beg = deg_off[node], end = deg_off[node + 1];
    float ald[4];
#pragma unroll
    for (int hh = 0; hh < 4; hh++) ald[hh] = al_d[node * 4 + hh];
    float acc[4] = {0.f, 0.f, 0.f, 0.f};
    float s[4] = {0.f, 0.f, 0.f, 0.f};
    for (int k = beg; k < end; k++) {
        int src = csr_src[k];
        const float* alsrow = al_s + src * 4;
        const float* hrow = h_lin + (size_t)src * 256;
#pragma unroll
        for (int hh = 0; hh < 4; hh++) {
            float p = __expf(lrelu(alsrow[hh] + ald[hh]));
            s[hh] += p;
            acc[hh] += p * hrow[hh * 64 + lane];
        }
    }
#pragma unroll
    for (int hh = 0; hh < 4; hh++) {
        float o = acc[hh] / (s[hh] + 1e-16f) + b_feat[hh * 64 + lane];
        h1[(size_t)node * 256 + hh * 64 + lane] = eluf(o);
    }
}

// ---------------- phase B: node_att, scaled linear transforms, alphas, elu outputs ----------------
// block 256 threads = 32 nodes; h1 tile in LDS.
__global__ __launch_bounds__(256) void phaseB_kernel(
    const float* __restrict__ h1, const float* __restrict__ W_mlp, const float* __restrict__ b_mlp,
    const float* __restrict__ W_obj, const float* __restrict__ W_ctx, const float* __restrict__ W_co,
    const float* __restrict__ as_obj, const float* __restrict__ ad_obj,
    const float* __restrict__ as_ctx, const float* __restrict__ ad_ctx,
    const float* __restrict__ as_co, const float* __restrict__ ad_co,
    float* __restrict__ g_obj, float* __restrict__ g_ctx, float* __restrict__ g_co,
    float* __restrict__ als2, float* __restrict__ ald2,  // [3][N][2]
    float* __restrict__ out_xo, float* __restrict__ out_xc) {
    __shared__ float ht[32 * 256];
    __shared__ float dots[32][52];  // [0..1]=mlp, [2..17]=obj, [18..33]=ctx, [34..49]=co, [50..51]=att
    int tid = threadIdx.x;
    int node0 = blockIdx.x * 32;
    const float4* hg = reinterpret_cast<const float4*>(h1) + (size_t)node0 * 64;
    float4* ht4 = reinterpret_cast<float4*>(ht);
    int maxf4 = (N_NODES - node0) * 64;
#pragma unroll
    for (int i = 0; i < 8; i++) {
        int f4 = tid + i * 256;
        float4 v = make_float4(0.f, 0.f, 0.f, 0.f);
        if (f4 < maxf4) v = hg[f4];
        ht4[f4] = v;
    }
    __syncthreads();

    // 32 nodes x 13 dot-tasks (12 col-groups-of-4 across 3 W's + 1 mlp pair)
    for (int t = tid; t < 32 * 13; t += 256) {
        int r = t / 13;
        int jj = t - r * 13;
        if (jj < 12) {
            int m = jj >> 2, q = jj & 3;
            const float* Wm = (m == 0) ? W_obj : (m == 1) ? W_ctx : W_co;
            float ax = 0.f, ay = 0.f, az = 0.f, aw = 0.f;
            for (int k = 0; k < 256; k += 4) {
                float4 hv = ht4[r * 64 + (k >> 2)];
                float4 w0 = *reinterpret_cast<const float4*>(Wm + (k + 0) * 16 + q * 4);
                float4 w1 = *reinterpret_cast<const float4*>(Wm + (k + 1) * 16 + q * 4);
                float4 w2 = *reinterpret_cast<const float4*>(Wm + (k + 2) * 16 + q * 4);
                float4 w3 = *reinterpret_cast<const float4*>(Wm + (k + 3) * 16 + q * 4);
                ax += hv.x * w0.x + hv.y * w1.x + hv.z * w2.x + hv.w * w3.x;
                ay += hv.x * w0.y + hv.y * w1.y + hv.z * w2.y + hv.w * w3.y;
                az += hv.x * w0.z + hv.y * w1.z + hv.z * w2.z + hv.w * w3.z;
                aw += hv.x * w0.w + hv.y * w1.w + hv.z * w2.w + hv.w * w3.w;
            }
            dots[r][2 + m * 16 + q * 4 + 0] = ax;
            dots[r][2 + m * 16 + q * 4 + 1] = ay;
            dots[r][2 + m * 16 + q * 4 + 2] = az;
            dots[r][2 + m * 16 + q * 4 + 3] = aw;
        } else {
            float a0 = 0.f, a1 = 0.f;
            for (int k = 0; k < 256; k += 4) {
                float4 hv = ht4[r * 64 + (k >> 2)];
                float4 wA = *reinterpret_cast<const float4*>(W_mlp + k * 2);      // rows k,k+1
                float4 wB = *reinterpret_cast<const float4*>(W_mlp + k * 2 + 4);  // rows k+2,k+3
                a0 += hv.x * wA.x + hv.y * wA.z + hv.z * wB.x + hv.w * wB.z;
                a1 += hv.x * wA.y + hv.y * wA.w + hv.z * wB.y + hv.w * wB.w;
            }
            dots[r][0] = a0;
            dots[r][1] = a1;
        }
    }
    __syncthreads();

    if (tid < 32) {
        int r = tid;
        int node = node0 + r;
        if (node < N_NODES) {
            float l0 = dots[r][0] + b_mlp[0], l1 = dots[r][1] + b_mlp[1];
            float mx = fmaxf(l0, l1);
            float e0 = __expf(l0 - mx), e1 = __expf(l1 - mx);
            float inv = 1.f / (e0 + e1);
            float a0 = e0 * inv, a1 = e1 * inv;
            dots[r][50] = a0;
            dots[r][51] = a1;
            float scales[3] = {a0, a1, 1.f};
            float* gptr[3] = {g_obj, g_ctx, g_co};
            const float* asp[3] = {as_obj, as_ctx, as_co};
            const float* adp[3] = {ad_obj, ad_ctx, ad_co};
#pragma unroll
            for (int v = 0; v < 3; v++) {
                float s0 = 0.f, s1 = 0.f, d0 = 0.f, d1 = 0.f;
#pragma unroll
                for (int i = 0; i < 16; i++) {
                    float gv = scales[v] * dots[r][2 + v * 16 + i];
                    gptr[v][(size_t)node * 16 + i] = gv;
                    float pas = gv * asp[v][i];
                    float pad = gv * adp[v][i];
                    if (i < 8) { s0 += pas; d0 += pad; } else { s1 += pas; d1 += pad; }
                }
                als2[((size_t)v * N_NODES + node) * 2 + 0] = s0;
                als2[((size_t)v * N_NODES + node) * 2 + 1] = s1;
                ald2[((size_t)v * N_NODES + node) * 2 + 0] = d0;
                ald2[((size_t)v * N_NODES + node) * 2 + 1] = d1;
            }
        }
    }
    __syncthreads();

    // elu(xo), elu(xc) outputs — coalesced
    {
        int c = tid;
        for (int r = 0; r < 32; r++) {
            int node = node0 + r;
            if (node >= N_NODES) break;
            float a0 = dots[r][50], a1 = dots[r][51];
            float hv = ht[r * 256 + c];
            out_xo[(size_t)node * 256 + c] = eluf(a0 * hv);
            out_xc[(size_t)node * 256 + c] = eluf(a1 * hv);
        }
    }
}

// ---------------- fused conv2 aggregation (obj/ctx/co) ----------------
// one wave per dst node; lane = v*16 + head*8 + c  (v in 0..2 active, lanes 48..63 mirror v=2)
__global__ __launch_bounds__(256) void conv2_aggregate(const int* __restrict__ deg_off,
                                                       const int* __restrict__ csr_src,
                                                       const float* __restrict__ g_obj,
                                                       const float* __restrict__ g_ctx,
                                                       const float* __restrict__ g_co,
                                                       const float* __restrict__ als2,
                                                       const float* __restrict__ ald2,
                                                       const float* __restrict__ b_obj,
                                                       const float* __restrict__ b_ctx,
                                                       const float* __restrict__ b_co,
                                                       float* __restrict__ out) {
    int wave = threadIdx.x >> 6;
    int lane = threadIdx.x & 63;
    int node = blockIdx.x * 4 + wave;
    if (node >= N_NODES) return;
    int v = lane >> 4;
    if (v > 2) v = 2;
    int head = (lane >> 3) & 1;
    int c = lane & 7;
    const float* g = (v == 0) ? g_obj : (v == 1) ? g_ctx : g_co;
    const float* bb = (v == 0) ? b_obj : (v == 1) ? b_ctx : b_co;
    const float* als = als2 + (size_t)v * N_NODES * 2;
    float ald = ald2[(size_t)v * N_NODES * 2 + node * 2 + head];
    int beg = deg_off[node], end = deg_off[node + 1];
    float acc = 0.f, s = 0.f;
    for (int k = beg; k < end; k++) {
        int src = csr_src[k];
        float p = __expf(lrelu(als[src * 2 + head] + ald));
        s += p;
        acc += p * g[(size_t)src * 16 + head * 8 + c];
    }
    float o = acc / (s + 1e-16f);
    float mean = 0.5f * (o + __shfl_xor(o, 8)) + bb[c];
    // log_softmax over the 8 channels (8-lane group)
    float mx = mean;
#pragma unroll
    for (int d = 1; d < 8; d <<= 1) mx = fmaxf(mx, __shfl_xor(mx, d));
    float ex = __expf(mean - mx);
    float ss = ex;
#pragma unroll
    for (int d = 1; d < 8; d <<= 1) ss += __shfl_xor(ss, d);
    float res = (mean - mx) - __logf(ss);
    if (lane < 48 && head == 0) out[(size_t)v * (N_NODES * 8) + node * 8 + c] = res;
}

// ---------------- launch ----------------
extern "C" void kernel_launch(void* const* d_in, const int* in_sizes, int n_in, void* d_out,
                              int out_size, void* d_ws, size_t ws_size, hipStream_t stream) {
    const float* x = (const float*)d_in[0];
    const int* ei = (const int*)d_in[1];  // int64 in reference -> int32 from harness
    const float* W_feat = (const float*)d_in[2];
    const float* a_src_feat = (const float*)d_in[3];
    const float* a_dst_feat = (const float*)d_in[4];
    const float* b_feat = (const float*)d_in[5];
    const float* W_mlp = (const float*)d_in[6];
    const float* b_mlp = (const float*)d_in[7];
    const float* W_obj = (const float*)d_in[8];
    const float* as_obj = (const float*)d_in[9];
    const float* ad_obj = (const float*)d_in[10];
    const float* b_obj = (const float*)d_in[11];
    const float* W_ctx = (const float*)d_in[12];
    const float* as_ctx = (const float*)d_in[13];
    const float* ad_ctx = (const float*)d_in[14];
    const float* b_ctx = (const float*)d_in[15];
    const float* W_co = (const float*)d_in[16];
    const float* as_co = (const float*)d_in[17];
    const float* ad_co = (const float*)d_in[18];
    const float* b_co = (const float*)d_in[19];
    float* out = (float*)d_out;

    char* w = (char*)d_ws;
    auto alloc = [&](size_t bytes) {
        void* p = (void*)w;
        w += (bytes + 255) & ~(size_t)255;
        return p;
    };
    int* cursor = (int*)alloc((size_t)N_NODES * 4);       // deg counts, then scatter cursor
    int* deg_off = (int*)alloc((size_t)(N_NODES + 1) * 4);
    int* csr_src = (int*)alloc((size_t)ET * 4);
    float* h_lin1 = (float*)alloc((size_t)N_NODES * 256 * 4);
    float* al_s1 = (float*)alloc((size_t)N_NODES * 4 * 4);
    float* al_d1 = (float*)alloc((size_t)N_NODES * 4 * 4);
    float* h1 = (float*)alloc((size_t)N_NODES * 256 * 4);
    float* g_obj = (float*)alloc((size_t)N_NODES * 16 * 4);
    float* g_ctx = (float*)alloc((size_t)N_NODES * 16 * 4);
    float* g_co = (float*)alloc((size_t)N_NODES * 16 * 4);
    float* als2 = (float*)alloc((size_t)3 * N_NODES * 2 * 4);
    float* ald2 = (float*)alloc((size_t)3 * N_NODES * 2 * 4);

    float* out_xo_logis = out;                       // [N,8] x3 convs
    float* out_xo = out + (size_t)3 * N_NODES * 8;   // [N,256]
    float* out_xc = out_xo + (size_t)N_NODES * 256;  // [N,256]

    // CSR build
    zero_kernel<<<(N_NODES + 255) / 256, 256, 0, stream>>>(cursor, N_NODES);
    hist_kernel<<<(ET + 255) / 256, 256, 0, stream>>>(ei, cursor);
    scan_kernel<<<1, SCAN_NT, 0, stream>>>(cursor, deg_off);
    scatter_kernel<<<(ET + 255) / 256, 256, 0, stream>>>(ei, cursor, csr_src);

    // conv1
    gemm1_kernel<<<(N_NODES + 31) / 32, 256, 0, stream>>>(x, W_feat, a_src_feat, a_dst_feat,
                                                          h_lin1, al_s1, al_d1);
    conv1_aggregate<<<(N_NODES + 3) / 4, 256, 0, stream>>>(deg_off, csr_src, h_lin1, al_s1, al_d1,
                                                           b_feat, h1);
    // phase B (node_att, scaled transforms, alphas, elu outputs)
    phaseB_kernel<<<(N_NODES + 31) / 32, 256, 0, stream>>>(
        h1, W_mlp, b_mlp, W_obj, W_ctx, W_co, as_obj, ad_obj, as_ctx, ad_ctx, as_co, ad_co, g_obj,
        g_ctx, g_co, als2, ald2, out_xo, out_xc);
    // fused conv2 x3
    conv2_aggregate<<<(N_NODES + 3) / 4, 256, 0, stream>>>(deg_off, csr_src, g_obj, g_ctx, g_co,
                                                           als2, ald2, b_obj, b_ctx, b_co,
                                                           out_xo_logis);
}

// Round 3
// 701.031 us; speedup vs baseline: 1.1427x; 1.1427x over previous
//
#include <hip/hip_runtime.h>
#include <hip/hip_bf16.h>

#define N_NODES 50000
#define N_EDGES 800000
#define ET (N_EDGES + N_NODES)   // edges + self loops = 850000
#define IN_DIM 128
#define F1 256                   // H1*HID
#define H1 4
#define HID 64
#define H2 2
#define OUTC 8
#define F2 16                    // H2*OUTC

typedef unsigned short u16;
typedef unsigned int u32;

static __device__ __forceinline__ float lrelu(float x) { return x > 0.f ? x : 0.2f * x; }
static __device__ __forceinline__ float eluf(float x) { return x > 0.f ? x : __expf(x) - 1.f; }
static __device__ __forceinline__ u16 f2bf(float x) {
    __hip_bfloat16 b(x);
    return *reinterpret_cast<u16*>(&b);
}

// ---------------- CSR build ----------------
__global__ void zero_kernel(int* p, int n) {
    int i = blockIdx.x * blockDim.x + threadIdx.x;
    if (i < n) p[i] = 0;
}

// edge_index arrives as int32 (harness converts integer inputs to int32).
__global__ void hist_kernel(const int* __restrict__ ei, int* __restrict__ deg) {
    int e = blockIdx.x * blockDim.x + threadIdx.x;
    if (e >= ET) return;
    int dst = (e < N_EDGES) ? ei[N_EDGES + e] : (e - N_EDGES);
    atomicAdd(&deg[dst], 1);
}

#define SCAN_NT 1024
__global__ __launch_bounds__(SCAN_NT) void scan_kernel(int* __restrict__ deg,
                                                       int* __restrict__ off) {
    __shared__ int sums[SCAN_NT];
    const int ITEMS = (N_NODES + SCAN_NT - 1) / SCAN_NT;  // 49
    int t = threadIdx.x;
    int base = t * ITEMS;
    int s = 0;
    for (int i = 0; i < ITEMS; i++) {
        int idx = base + i;
        if (idx < N_NODES) s += deg[idx];
    }
    sums[t] = s;
    __syncthreads();
    for (int d = 1; d < SCAN_NT; d <<= 1) {
        int v = (t >= d) ? sums[t - d] : 0;
        __syncthreads();
        sums[t] += v;
        __syncthreads();
    }
    int run = (t == 0) ? 0 : sums[t - 1];
    for (int i = 0; i < ITEMS; i++) {
        int idx = base + i;
        if (idx < N_NODES) {
            int v = deg[idx];
            off[idx] = run;
            deg[idx] = run;  // becomes cursor for scatter
            run += v;
        }
    }
    if (t == SCAN_NT - 1) off[N_NODES] = run;
}

__global__ void scatter_kernel(const int* __restrict__ ei, int* __restrict__ cursor,
                               int* __restrict__ csr_src) {
    int e = blockIdx.x * blockDim.x + threadIdx.x;
    if (e >= ET) return;
    int src, dst;
    if (e < N_EDGES) {
        src = ei[e];
        dst = ei[N_EDGES + e];
    } else {
        src = dst = e - N_EDGES;
    }
    int pos = atomicAdd(&cursor[dst], 1);
    csr_src[pos] = src;
}

// ---------------- GEMM1: h_lin = x @ W_feat (fp32 compute), store bf16 interleaved ----------------
// h_bf layout: [node][64 channels][4 heads] bf16  -> per lane one uint2 gather in conv1.
__global__ __launch_bounds__(256) void gemm1_kernel(const float* __restrict__ x,
                                                    const float* __restrict__ Wf,
                                                    const float* __restrict__ a_src,
                                                    const float* __restrict__ a_dst,
                                                    u16* __restrict__ h_bf,
                                                    float* __restrict__ al_s,
                                                    float* __restrict__ al_d) {
    __shared__ float xt[32 * 128];  // 16 KB; reused as bf16 staging (8192 u16) later
    int tid = threadIdx.x;
    int node0 = blockIdx.x * 32;
    const float4* xg = reinterpret_cast<const float4*>(x) + (size_t)node0 * 32;
    float4* xt4 = reinterpret_cast<float4*>(xt);
    int maxf4 = (N_NODES - node0) * 32;
#pragma unroll
    for (int i = 0; i < 4; i++) {
        int f4 = tid + i * 256;
        float4 v = make_float4(0.f, 0.f, 0.f, 0.f);
        if (f4 < maxf4) v = xg[f4];
        xt4[f4] = v;
    }
    __syncthreads();

    float acc[32];
#pragma unroll
    for (int r = 0; r < 32; r++) acc[r] = 0.f;
    int j = tid;
    for (int kc = 0; kc < 128; kc += 8) {
        float w[8];
#pragma unroll
        for (int kk = 0; kk < 8; kk++) w[kk] = Wf[(kc + kk) * 256 + j];
#pragma unroll
        for (int r = 0; r < 32; r++) {
            float4 a0 = xt4[r * 32 + (kc >> 2)];
            float4 a1 = xt4[r * 32 + (kc >> 2) + 1];
            acc[r] += a0.x * w[0] + a0.y * w[1] + a0.z * w[2] + a0.w * w[3] +
                      a1.x * w[4] + a1.y * w[5] + a1.z * w[6] + a1.w * w[7];
        }
    }

    // alpha reductions (register-only): wave w == head w
    {
        int head = tid >> 6;
        int lane = tid & 63;
        float asv = a_src[head * 64 + lane];
        float adv = a_dst[head * 64 + lane];
        for (int r = 0; r < 32; r++) {
            float ps = acc[r] * asv;
            float pd = acc[r] * adv;
#pragma unroll
            for (int d = 1; d < 64; d <<= 1) {
                ps += __shfl_xor(ps, d);
                pd += __shfl_xor(pd, d);
            }
            int node = node0 + r;
            if (lane == 0 && node < N_NODES) {
                al_s[node * 4 + head] = ps;
                al_d[node * 4 + head] = pd;
            }
        }
    }

    // bf16 transpose-staging in LDS: [r][ch][head] u16, then coalesced uint2 copy-out
    __syncthreads();  // done reading xt
    u16* hs = reinterpret_cast<u16*>(xt);
    int headj = tid >> 6, chj = tid & 63;
#pragma unroll
    for (int r = 0; r < 32; r++) hs[r * 256 + chj * 4 + headj] = f2bf(acc[r]);
    __syncthreads();
    uint2* hq = reinterpret_cast<uint2*>(h_bf);
    const uint2* hsq = reinterpret_cast<const uint2*>(hs);
#pragma unroll
    for (int it = 0; it < 8; it++) {
        int idx = it * 256 + tid;            // uint2 index within block tile (2048 total)
        int node_local = idx >> 6;           // 64 uint2 per node
        if (node0 + node_local < N_NODES) hq[(size_t)node0 * 64 + idx] = hsq[idx];
    }
}

// ---------------- conv1 aggregation: one wave per dst node ----------------
__global__ __launch_bounds__(256) void conv1_aggregate(const int* __restrict__ deg_off,
                                                       const int* __restrict__ csr_src,
                                                       const u16* __restrict__ h_bf,
                                                       const float* __restrict__ al_s,
                                                       const float* __restrict__ al_d,
                                                       const float* __restrict__ b_feat,
                                                       float* __restrict__ h1) {
    int wave = threadIdx.x >> 6;
    int lane = threadIdx.x & 63;
    int node = blockIdx.x * 4 + wave;
    if (node >= N_NODES) return;
    int beg = deg_off[node], end = deg_off[node + 1];
    float4 aldv = *reinterpret_cast<const float4*>(al_d + node * 4);
    const uint2* hq = reinterpret_cast<const uint2*>(h_bf);
    float acc0 = 0.f, acc1 = 0.f, acc2 = 0.f, acc3 = 0.f;
    float s0 = 0.f, s1 = 0.f, s2 = 0.f, s3 = 0.f;

    int k = beg;
    for (; k + 4 <= end; k += 4) {
        int sa = csr_src[k], sb = csr_src[k + 1], sc = csr_src[k + 2], sd = csr_src[k + 3];
        float4 Aa = *reinterpret_cast<const float4*>(al_s + sa * 4);
        float4 Ab = *reinterpret_cast<const float4*>(al_s + sb * 4);
        float4 Ac = *reinterpret_cast<const float4*>(al_s + sc * 4);
        float4 Ad = *reinterpret_cast<const float4*>(al_s + sd * 4);
        uint2 ha = hq[(size_t)sa * 64 + lane];
        uint2 hb = hq[(size_t)sb * 64 + lane];
        uint2 hc = hq[(size_t)sc * 64 + lane];
        uint2 hd = hq[(size_t)sd * 64 + lane];
#define C1_EDGE(A, h)                                                        \
        {                                                                    \
            float p0 = __expf(lrelu(A.x + aldv.x));                          \
            float p1 = __expf(lrelu(A.y + aldv.y));                          \
            float p2 = __expf(lrelu(A.z + aldv.z));                          \
            float p3 = __expf(lrelu(A.w + aldv.w));                          \
            s0 += p0; s1 += p1; s2 += p2; s3 += p3;                          \
            acc0 += p0 * __uint_as_float(h.x << 16);                         \
            acc1 += p1 * __uint_as_float(h.x & 0xffff0000u);                 \
            acc2 += p2 * __uint_as_float(h.y << 16);                         \
            acc3 += p3 * __uint_as_float(h.y & 0xffff0000u);                 \
        }
        C1_EDGE(Aa, ha)
        C1_EDGE(Ab, hb)
        C1_EDGE(Ac, hc)
        C1_EDGE(Ad, hd)
    }
    for (; k < end; k++) {
        int sa = csr_src[k];
        float4 Aa = *reinterpret_cast<const float4*>(al_s + sa * 4);
        uint2 ha = hq[(size_t)sa * 64 + lane];
        C1_EDGE(Aa, ha)
    }
#undef C1_EDGE
    h1[(size_t)node * 256 + 0 * 64 + lane] = eluf(acc0 / (s0 + 1e-16f) + b_feat[0 * 64 + lane]);
    h1[(size_t)node * 256 + 1 * 64 + lane] = eluf(acc1 / (s1 + 1e-16f) + b_feat[1 * 64 + lane]);
    h1[(size_t)node * 256 + 2 * 64 + lane] = eluf(acc2 / (s2 + 1e-16f) + b_feat[2 * 64 + lane]);
    h1[(size_t)node * 256 + 3 * 64 + lane] = eluf(acc3 / (s3 + 1e-16f) + b_feat[3 * 64 + lane]);
}

// ---------------- phase B: node_att, scaled linear transforms, alphas, elu outputs ----------------
__global__ __launch_bounds__(256) void phaseB_kernel(
    const float* __restrict__ h1, const float* __restrict__ W_mlp, const float* __restrict__ b_mlp,
    const float* __restrict__ W_obj, const float* __restrict__ W_ctx, const float* __restrict__ W_co,
    const float* __restrict__ as_obj, const float* __restrict__ ad_obj,
    const float* __restrict__ as_ctx, const float* __restrict__ ad_ctx,
    const float* __restrict__ as_co, const float* __restrict__ ad_co,
    float* __restrict__ g_all,   // [N][3][16]
    float* __restrict__ att2,    // [N][16]: 0..5 = al_src(v,h), 8..13 = al_dst(v,h)
    float* __restrict__ out_xo, float* __restrict__ out_xc) {
    __shared__ float ht[32 * 256];
    __shared__ float dots[32][52];
    int tid = threadIdx.x;
    int node0 = blockIdx.x * 32;
    const float4* hg = reinterpret_cast<const float4*>(h1) + (size_t)node0 * 64;
    float4* ht4 = reinterpret_cast<float4*>(ht);
    int maxf4 = (N_NODES - node0) * 64;
#pragma unroll
    for (int i = 0; i < 8; i++) {
        int f4 = tid + i * 256;
        float4 v = make_float4(0.f, 0.f, 0.f, 0.f);
        if (f4 < maxf4) v = hg[f4];
        ht4[f4] = v;
    }
    __syncthreads();

    for (int t = tid; t < 32 * 13; t += 256) {
        int r = t / 13;
        int jj = t - r * 13;
        if (jj < 12) {
            int m = jj >> 2, q = jj & 3;
            const float* Wm = (m == 0) ? W_obj : (m == 1) ? W_ctx : W_co;
            float ax = 0.f, ay = 0.f, az = 0.f, aw = 0.f;
            for (int k = 0; k < 256; k += 4) {
                float4 hv = ht4[r * 64 + (k >> 2)];
                float4 w0 = *reinterpret_cast<const float4*>(Wm + (k + 0) * 16 + q * 4);
                float4 w1 = *reinterpret_cast<const float4*>(Wm + (k + 1) * 16 + q * 4);
                float4 w2 = *reinterpret_cast<const float4*>(Wm + (k + 2) * 16 + q * 4);
                float4 w3 = *reinterpret_cast<const float4*>(Wm + (k + 3) * 16 + q * 4);
                ax += hv.x * w0.x + hv.y * w1.x + hv.z * w2.x + hv.w * w3.x;
                ay += hv.x * w0.y + hv.y * w1.y + hv.z * w2.y + hv.w * w3.y;
                az += hv.x * w0.z + hv.y * w1.z + hv.z * w2.z + hv.w * w3.z;
                aw += hv.x * w0.w + hv.y * w1.w + hv.z * w2.w + hv.w * w3.w;
            }
            dots[r][2 + m * 16 + q * 4 + 0] = ax;
            dots[r][2 + m * 16 + q * 4 + 1] = ay;
            dots[r][2 + m * 16 + q * 4 + 2] = az;
            dots[r][2 + m * 16 + q * 4 + 3] = aw;
        } else {
            float a0 = 0.f, a1 = 0.f;
            for (int k = 0; k < 256; k += 4) {
                float4 hv = ht4[r * 64 + (k >> 2)];
                float4 wA = *reinterpret_cast<const float4*>(W_mlp + k * 2);
                float4 wB = *reinterpret_cast<const float4*>(W_mlp + k * 2 + 4);
                a0 += hv.x * wA.x + hv.y * wA.z + hv.z * wB.x + hv.w * wB.z;
                a1 += hv.x * wA.y + hv.y * wA.w + hv.z * wB.y + hv.w * wB.w;
            }
            dots[r][0] = a0;
            dots[r][1] = a1;
        }
    }
    __syncthreads();

    if (tid < 32) {
        int r = tid;
        int node = node0 + r;
        if (node < N_NODES) {
            float l0 = dots[r][0] + b_mlp[0], l1 = dots[r][1] + b_mlp[1];
            float mx = fmaxf(l0, l1);
            float e0 = __expf(l0 - mx), e1 = __expf(l1 - mx);
            float inv = 1.f / (e0 + e1);
            float a0 = e0 * inv, a1 = e1 * inv;
            dots[r][50] = a0;
            dots[r][51] = a1;
            float scales[3] = {a0, a1, 1.f};
            const float* asp[3] = {as_obj, as_ctx, as_co};
            const float* adp[3] = {ad_obj, ad_ctx, ad_co};
#pragma unroll
            for (int v = 0; v < 3; v++) {
                float ss0 = 0.f, ss1 = 0.f, dd0 = 0.f, dd1 = 0.f;
#pragma unroll
                for (int i = 0; i < 16; i++) {
                    float gv = scales[v] * dots[r][2 + v * 16 + i];
                    g_all[(size_t)node * 48 + v * 16 + i] = gv;
                    float pas = gv * asp[v][i];
                    float pad = gv * adp[v][i];
                    if (i < 8) { ss0 += pas; dd0 += pad; } else { ss1 += pas; dd1 += pad; }
                }
                att2[(size_t)node * 16 + v * 2 + 0] = ss0;
                att2[(size_t)node * 16 + v * 2 + 1] = ss1;
                att2[(size_t)node * 16 + 8 + v * 2 + 0] = dd0;
                att2[(size_t)node * 16 + 8 + v * 2 + 1] = dd1;
            }
        }
    }
    __syncthreads();

    {
        int c = tid;
        for (int r = 0; r < 32; r++) {
            int node = node0 + r;
            if (node >= N_NODES) break;
            float a0 = dots[r][50], a1 = dots[r][51];
            float hv = ht[r * 256 + c];
            out_xo[(size_t)node * 256 + c] = eluf(a0 * hv);
            out_xc[(size_t)node * 256 + c] = eluf(a1 * hv);
        }
    }
}

// ---------------- fused conv2 aggregation (obj/ctx/co) ----------------
// one wave per dst node; lane = v*16 + head*8 + c (lanes 48..63 duplicate v=2, no writes)
__global__ __launch_bounds__(256) void conv2_aggregate(const int* __restrict__ deg_off,
                                                       const int* __restrict__ csr_src,
                                                       const float* __restrict__ g_all,
                                                       const float* __restrict__ att2,
                                                       const float* __restrict__ b_obj,
                                                       const float* __restrict__ b_ctx,
                                                       const float* __restrict__ b_co,
                                                       float* __restrict__ out) {
    int wave = threadIdx.x >> 6;
    int lane = threadIdx.x & 63;
    int node = blockIdx.x * 4 + wave;
    if (node >= N_NODES) return;
    int v = lane >> 4;
    if (v > 2) v = 2;
    int head = (lane >> 3) & 1;
    int c = lane & 7;
    int aidx = v * 2 + head;
    int gidx = v * 16 + head * 8 + c;
    const float* bb = (v == 0) ? b_obj : (v == 1) ? b_ctx : b_co;
    float ald = att2[(size_t)node * 16 + 8 + aidx];
    int beg = deg_off[node], end = deg_off[node + 1];
    float acc = 0.f, s = 0.f;
    int k = beg;
    for (; k + 4 <= end; k += 4) {
        int sa = csr_src[k], sb = csr_src[k + 1], sc = csr_src[k + 2], sd = csr_src[k + 3];
        float ea = att2[(size_t)sa * 16 + aidx];
        float eb = att2[(size_t)sb * 16 + aidx];
        float ec = att2[(size_t)sc * 16 + aidx];
        float ed = att2[(size_t)sd * 16 + aidx];
        float ga = g_all[(size_t)sa * 48 + gidx];
        float gb = g_all[(size_t)sb * 48 + gidx];
        float gc = g_all[(size_t)sc * 48 + gidx];
        float gd = g_all[(size_t)sd * 48 + gidx];
        float pa = __expf(lrelu(ea + ald));
        float pb = __expf(lrelu(eb + ald));
        float pc = __expf(lrelu(ec + ald));
        float pd = __expf(lrelu(ed + ald));
        s += pa + pb + pc + pd;
        acc += pa * ga + pb * gb + pc * gc + pd * gd;
    }
    for (; k < end; k++) {
        int sa = csr_src[k];
        float p = __expf(lrelu(att2[(size_t)sa * 16 + aidx] + ald));
        s += p;
        acc += p * g_all[(size_t)sa * 48 + gidx];
    }
    float o = acc / (s + 1e-16f);
    float mean = 0.5f * (o + __shfl_xor(o, 8)) + bb[c];
    float mx = mean;
#pragma unroll
    for (int d = 1; d < 8; d <<= 1) mx = fmaxf(mx, __shfl_xor(mx, d));
    float ex = __expf(mean - mx);
    float ss = ex;
#pragma unroll
    for (int d = 1; d < 8; d <<= 1) ss += __shfl_xor(ss, d);
    float res = (mean - mx) - __logf(ss);
    if (lane < 48 && head == 0) out[(size_t)v * (N_NODES * 8) + node * 8 + c] = res;
}

// ---------------- launch ----------------
extern "C" void kernel_launch(void* const* d_in, const int* in_sizes, int n_in, void* d_out,
                              int out_size, void* d_ws, size_t ws_size, hipStream_t stream) {
    const float* x = (const float*)d_in[0];
    const int* ei = (const int*)d_in[1];  // int64 in reference -> int32 from harness
    const float* W_feat = (const float*)d_in[2];
    const float* a_src_feat = (const float*)d_in[3];
    const float* a_dst_feat = (const float*)d_in[4];
    const float* b_feat = (const float*)d_in[5];
    const float* W_mlp = (const float*)d_in[6];
    const float* b_mlp = (const float*)d_in[7];
    const float* W_obj = (const float*)d_in[8];
    const float* as_obj = (const float*)d_in[9];
    const float* ad_obj = (const float*)d_in[10];
    const float* b_obj = (const float*)d_in[11];
    const float* W_ctx = (const float*)d_in[12];
    const float* as_ctx = (const float*)d_in[13];
    const float* ad_ctx = (const float*)d_in[14];
    const float* b_ctx = (const float*)d_in[15];
    const float* W_co = (const float*)d_in[16];
    const float* as_co = (const float*)d_in[17];
    const float* ad_co = (const float*)d_in[18];
    const float* b_co = (const float*)d_in[19];
    float* out = (float*)d_out;

    char* w = (char*)d_ws;
    auto alloc = [&](size_t bytes) {
        void* p = (void*)w;
        w += (bytes + 255) & ~(size_t)255;
        return p;
    };
    int* cursor = (int*)alloc((size_t)N_NODES * 4);
    int* deg_off = (int*)alloc((size_t)(N_NODES + 1) * 4);
    int* csr_src = (int*)alloc((size_t)ET * 4);
    u16* h_bf = (u16*)alloc((size_t)N_NODES * 256 * 2);
    float* al_s1 = (float*)alloc((size_t)N_NODES * 4 * 4);
    float* al_d1 = (float*)alloc((size_t)N_NODES * 4 * 4);
    float* h1 = (float*)alloc((size_t)N_NODES * 256 * 4);
    float* g_all = (float*)alloc((size_t)N_NODES * 48 * 4);
    float* att2 = (float*)alloc((size_t)N_NODES * 16 * 4);

    float* out_xo_logis = out;                       // [N,8] x3 convs
    float* out_xo = out + (size_t)3 * N_NODES * 8;   // [N,256]
    float* out_xc = out_xo + (size_t)N_NODES * 256;  // [N,256]

    // CSR build
    zero_kernel<<<(N_NODES + 255) / 256, 256, 0, stream>>>(cursor, N_NODES);
    hist_kernel<<<(ET + 255) / 256, 256, 0, stream>>>(ei, cursor);
    scan_kernel<<<1, SCAN_NT, 0, stream>>>(cursor, deg_off);
    scatter_kernel<<<(ET + 255) / 256, 256, 0, stream>>>(ei, cursor, csr_src);

    // conv1
    gemm1_kernel<<<(N_NODES + 31) / 32, 256, 0, stream>>>(x, W_feat, a_src_feat, a_dst_feat,
                                                          h_bf, al_s1, al_d1);
    conv1_aggregate<<<(N_NODES + 3) / 4, 256, 0, stream>>>(deg_off, csr_src, h_bf, al_s1, al_d1,
                                                           b_feat, h1);
    // phase B
    phaseB_kernel<<<(N_NODES + 31) / 32, 256, 0, stream>>>(
        h1, W_mlp, b_mlp, W_obj, W_ctx, W_co, as_obj, ad_obj, as_ctx, ad_ctx, as_co, ad_co, g_all,
        att2, out_xo, out_xc);
    // fused conv2 x3
    conv2_aggregate<<<(N_NODES + 3) / 4, 256, 0, stream>>>(deg_off, csr_src, g_all, att2, b_obj,
                                                           b_ctx, b_co, out_xo_logis);
}